// Round 1
// baseline (502.644 us; speedup 1.0000x reference)
//
#include <hip/hip_runtime.h>
#include <hip/hip_bf16.h>
#include <cstdint>
#include <cstddef>

typedef __fp16 f16_t;
typedef __attribute__((ext_vector_type(8))) __fp16 f16x8;
typedef __attribute__((ext_vector_type(4))) __fp16 f16x4;
typedef __attribute__((ext_vector_type(2))) __fp16 h2_t;
typedef __attribute__((ext_vector_type(4))) float floatx4;

// ---------------------------------------------------------------- helpers
__device__ __forceinline__ void async_copy_16B(const void* g, void* l) {
  __builtin_amdgcn_global_load_lds(
      (const __attribute__((address_space(1))) void*)g,
      (__attribute__((address_space(3))) void*)l, 16, 0, 0);
}

#define ISSUE_FENCE asm volatile("" ::: "memory")

// ---------------------------------------------------------------- prep
// Fused: cast x/w_in/w_out to f16 (5242880 float4s) and build packed f16
// weight-pair table wp[p][c], p=0..127:
//   p<126 : (w[p], w[p+1]) ; p==126 : (w[126], 0) ; p==127 : (0, w[0])
__global__ __launch_bounds__(256) void prep(
    const float* __restrict__ x, const float* __restrict__ w_in,
    const float* __restrict__ w_out, const float* __restrict__ w_dw,
    f16_t* __restrict__ x_h, f16_t* __restrict__ wi_h,
    f16_t* __restrict__ wo_h, h2_t* __restrict__ wp) {
  const int tid = blockIdx.x * 256 + threadIdx.x;
  if (tid < 5242880) {
    const float* src;
    f16_t* dst;
    int off;
    if (tid < 2097152) {
      src = x; dst = x_h; off = tid;
    } else if (tid < 4194304) {
      src = w_in; dst = wi_h; off = tid - 2097152;
    } else {
      src = w_out; dst = wo_h; off = tid - 4194304;
    }
    const float4 v = *(const float4*)(src + (size_t)off * 4);
    f16x4 o;
    o.x = (f16_t)v.x; o.y = (f16_t)v.y; o.z = (f16_t)v.z; o.w = (f16_t)v.w;
    *(f16x4*)(dst + (size_t)off * 4) = o;
  } else {
    const int idx = tid - 5242880;
    if (idx < 128 * 4096) {
      const int p = idx >> 12;
      const int c = idx & 4095;
      float a, b;
      if (p < 126) {
        a = w_dw[c * 127 + p]; b = w_dw[c * 127 + p + 1];
      } else if (p == 126) {
        a = w_dw[c * 127 + 126]; b = 0.f;
      } else {
        a = 0.f; b = w_dw[c * 127 + 0];
      }
      h2_t w;
      w.x = (f16_t)a; w.y = (f16_t)b;
      wp[idx] = w;
    }
  }
}

// ---------------------------------------------------------------- GEMM1
// 256x256 tile, BK=64, 8 waves (2 M x 4 N), 8-phase-per-2-tiles schedule
// (4 phases per K-tile), double-buffered 128 KiB LDS, counted vmcnt,
// XOR-swizzled LDS, setprio around MFMA, XCD-bijective block swizzle.
//
// LDS layout per buffer d (d*65536):
//   A[256][64] f16 at +0 (32 KB), B[256][64] f16 at +32768.
//   Row = 128 B = 8 x 16B slots. Physical slot s of row r holds k8-group
//   (s ^ (r&7)) -> ds_read of k-group g uses slot g^(r&7). Staging keeps
//   the LDS dest LINEAR (global_load_lds requirement) and applies the
//   inverse swizzle on the GLOBAL source column (both-sides rule).
//
// Stage units per K-tile (8 loads/thread/tile):
//   Bu-lo = B rows 0..127 (2 ld/thr), Bu-hi = B rows 128..255 (2),
//   Au_q  = A rows {32q..32q+31} u {128+32q..+31} (1 ld/thr, q=0..3)
//   = exactly the A rows consumed at phase q (by wm=0 and wm=1).
//
// Issue schedule (during tile t, for tile t+1):
//   phase0: Bu-lo | phase1: Bu-hi | phase2: Au_0,Au_1 | phase3: Au_2,Au_3
// Per-phase counted vmcnt (before the phase barrier; gates the NEXT
// phase's ds_reads; in-order vmcnt retirement):
//   phase0: vmcnt(4)  (all but {Au_2,Au_3,BuLo(t+1)x2} landed -> Au_1 ok)
//   phase1: vmcnt(5)  (-> Au_2 landed)
//   phase2: vmcnt(6)  (-> Au_3 landed)   <- steady-state 6, never 0
//   phase3: vmcnt(3)  (-> BuLo,BuHi,Au_0 of t+1 landed)
// Last tile (no prefetch): 2,1,0,-.
__global__ __launch_bounds__(512, 2) void gemm256_8p(
    const f16_t* __restrict__ A, const f16_t* __restrict__ B,
    f16_t* __restrict__ C, int M, int N, int K) {
  extern __shared__ char smem[];
  const int t = threadIdx.x;
  const int lane = t & 63;
  const int wave = t >> 6;
  const int wm = wave >> 2;  // 0..1 : 128-row half
  const int wn = wave & 3;   // 0..3 : 64-col strip

  // bijective XCD swizzle: grid=1024 (32x32 tiles), 1024 % 8 == 0
  const int bid = blockIdx.x;
  const int swz = (bid & 7) * 128 + (bid >> 3);
  const int m0 = (swz >> 5) * 256;
  const int n0 = (swz & 31) * 256;

  const int fr = lane & 15;
  const int ks = lane >> 4;  // k8-group within K=32 half

  auto stageB = [&](int d, int k0, int half) {
#pragma unroll
    for (int l = 0; l < 2; ++l) {
      const int q = l * 512 + t;
      const int row = half * 128 + (q >> 3);
      const int slot = q & 7;
      const int col = (slot ^ (row & 7)) * 8;  // inverse-swizzled source
      async_copy_16B(B + (size_t)(n0 + row) * K + k0 + col,
                     smem + d * 65536 + 32768 + row * 128 + slot * 16);
    }
  };
  auto stageA = [&](int d, int k0, int j) {
    const int blk = t >> 8;  // 0: rows 32j.., 1: rows 128+32j..
    const int row = j * 32 + blk * 128 + ((t & 255) >> 3);
    const int slot = t & 7;
    const int col = (slot ^ (row & 7)) * 8;
    async_copy_16B(A + (size_t)(m0 + row) * K + k0 + col,
                   smem + d * 65536 + row * 128 + slot * 16);
  };
  auto ldA = [&](int d, int R, int kslot) -> f16x8 {
    return *(const f16x8*)(smem + d * 65536 + R * 128 +
                           ((kslot ^ (R & 7)) << 4));
  };
  auto ldB = [&](int d, int R, int kslot) -> f16x8 {
    return *(const f16x8*)(smem + d * 65536 + 32768 + R * 128 +
                           ((kslot ^ (R & 7)) << 4));
  };

  floatx4 acc[8][4] = {};
  const int kTiles = K / 64;

  // prologue: tile 0 units, canonical order (fences pin issue order for
  // the vmcnt arithmetic)
  stageB(0, 0, 0); ISSUE_FENCE;
  stageB(0, 0, 1); ISSUE_FENCE;
  stageA(0, 0, 0); ISSUE_FENCE;
  stageA(0, 0, 1); ISSUE_FENCE;
  stageA(0, 0, 2); ISSUE_FENCE;
  stageA(0, 0, 3); ISSUE_FENCE;
  asm volatile("s_waitcnt vmcnt(3)" ::: "memory");  // BuLo,BuHi,Au_0 landed
  __builtin_amdgcn_s_barrier();

  f16x8 bf[4][2];
  for (int tt = 0; tt < kTiles; ++tt) {
    const int d = tt & 1;
    const int kn = (tt + 1) * 64;
    const bool pf = (tt + 1 < kTiles);
#pragma unroll
    for (int q = 0; q < 4; ++q) {
      // ds-reads for this phase (A quadrant; B once per tile, reg-resident)
      f16x8 af[2][2];
#pragma unroll
      for (int kh = 0; kh < 2; ++kh) {
#pragma unroll
        for (int ii = 0; ii < 2; ++ii)
          af[ii][kh] = ldA(d, wm * 128 + q * 32 + ii * 16 + fr, kh * 4 + ks);
        if (q == 0)
#pragma unroll
          for (int j = 0; j < 4; ++j)
            bf[j][kh] = ldB(d, wn * 64 + j * 16 + fr, kh * 4 + ks);
      }
      // prefetch-issue one unit of tile t+1 (writes buf d^1: not read
      // this tile; prior readers separated by >=1 barrier)
      if (pf) {
        if (q == 0) stageB(d ^ 1, kn, 0);
        else if (q == 1) stageB(d ^ 1, kn, 1);
        else if (q == 2) { stageA(d ^ 1, kn, 0); stageA(d ^ 1, kn, 1); }
        else { stageA(d ^ 1, kn, 2); stageA(d ^ 1, kn, 3); }
      }
      // counted vmcnt: gates NEXT phase's reads (every wave waits for its
      // own loads here; the barrier then makes the whole tile's DMA visible)
      if (pf) {
        if (q == 0)      asm volatile("s_waitcnt vmcnt(4)" ::: "memory");
        else if (q == 1) asm volatile("s_waitcnt vmcnt(5)" ::: "memory");
        else if (q == 2) asm volatile("s_waitcnt vmcnt(6)" ::: "memory");
        else             asm volatile("s_waitcnt vmcnt(3)" ::: "memory");
      } else {
        if (q == 0)      asm volatile("s_waitcnt vmcnt(2)" ::: "memory");
        else if (q == 1) asm volatile("s_waitcnt vmcnt(1)" ::: "memory");
        else if (q == 2) asm volatile("s_waitcnt vmcnt(0)" ::: "memory");
      }
      __builtin_amdgcn_s_barrier();
      __builtin_amdgcn_s_setprio(1);
#pragma unroll
      for (int kh = 0; kh < 2; ++kh)
#pragma unroll
        for (int ii = 0; ii < 2; ++ii)
#pragma unroll
          for (int j = 0; j < 4; ++j)
            acc[q * 2 + ii][j] = __builtin_amdgcn_mfma_f32_16x16x32_f16(
                af[ii][kh], bf[j][kh], acc[q * 2 + ii][j], 0, 0, 0);
      __builtin_amdgcn_s_setprio(0);
      __builtin_amdgcn_s_barrier();  // reads of this phase fully consumed
                                     // before anyone stages over old data
    }
  }

  // C/D layout: col = lane&15, row = (lane>>4)*4 + reg
  const int cr = (lane >> 4) * 4;
  const int cc = lane & 15;
#pragma unroll
  for (int i = 0; i < 8; ++i)
#pragma unroll
    for (int j = 0; j < 4; ++j)
#pragma unroll
      for (int r = 0; r < 4; ++r) {
        const int row = m0 + wm * 128 + i * 16 + cr + r;
        const int col = n0 + wn * 64 + j * 16 + cc;
        C[(size_t)row * N + col] = (f16_t)acc[i][j][r];
      }
}

// ---------------------------------------------------------------- GEMM2
// BK=128 variant for the long-K (K=4096) out-projection: 4x 32-col panels,
// 48 KB LDS (3 blocks/CU), 32 K-tiles -> half the barrier drains of BK=64.
// BM=128, BN=64; wave w computes rows [w*32, w*32+32) x all 64 cols.
__global__ __launch_bounds__(256) void gemm_bt_k128(
    const f16_t* __restrict__ A, const f16_t* __restrict__ B,
    float* __restrict__ C, int M, int N, int K) {
  constexpr int BM_ = 128, BN_ = 64, KP = 4;
  constexpr int NA = BM_ * 4 * KP;            // 2048 A-chunks per K-tile
  constexpr int NTOT = (BM_ + BN_) * 4 * KP;  // 3072 chunks
  constexpr int CPT = NTOT / 256;             // 12

  __shared__ f16_t smem[(BM_ + BN_) * 128];  // 48 KB
  const int t = threadIdx.x;
  const int lane = t & 63;
  const int wave = t >> 6;
  const int m0 = blockIdx.y * BM_;
  const int n0 = blockIdx.x * BN_;
  const int wr = wave * 32;
  const int fr = lane & 15;
  const int fk = (lane >> 4) * 8;

  floatx4 acc[2][4] = {};

  const int kTiles = K / 128;
  for (int kt = 0; kt < kTiles; ++kt) {
    const int k0 = kt * 128;
    __syncthreads();
#pragma unroll
    for (int it = 0; it < CPT; ++it) {
      const int p = it * 256 + t;
      const f16_t* gsrc;
      if (p < NA) {
        const int h = p >> 9;               // panel 0..3
        const int r = (p >> 2) & (BM_ - 1);
        const int kc = h * 32 + (p & 3) * 8;
        gsrc = A + (size_t)(m0 + r) * K + k0 + kc;
      } else {
        const int q = p - NA;
        const int h = q >> 8;
        const int r = (q >> 2) & (BN_ - 1);
        const int kc = h * 32 + (q & 3) * 8;
        gsrc = B + (size_t)(n0 + r) * K + k0 + kc;
      }
      async_copy_16B(gsrc, smem + p * 8);
    }
    __syncthreads();

#pragma unroll
    for (int h = 0; h < KP; ++h) {
      f16x8 af[2], bf[4];
#pragma unroll
      for (int i = 0; i < 2; ++i)
        af[i] = *(const f16x8*)(smem + h * BM_ * 32 + (wr + i * 16 + fr) * 32 + fk);
#pragma unroll
      for (int j = 0; j < 4; ++j)
        bf[j] = *(const f16x8*)(smem + NA * 8 + h * BN_ * 32 + (j * 16 + fr) * 32 + fk);
#pragma unroll
      for (int i = 0; i < 2; ++i)
#pragma unroll
        for (int j = 0; j < 4; ++j)
          acc[i][j] = __builtin_amdgcn_mfma_f32_16x16x32_f16(
              af[i], bf[j], acc[i][j], 0, 0, 0);
    }
  }

  const int cr = (lane >> 4) * 4;
  const int cc = lane & 15;
#pragma unroll
  for (int i = 0; i < 2; ++i)
#pragma unroll
    for (int j = 0; j < 4; ++j)
#pragma unroll
      for (int r = 0; r < 4; ++r) {
        const int row = m0 + wr + i * 16 + cr + r;
        const int col = n0 + j * 16 + cc;
        C[(size_t)row * N + col] = acc[i][j][r];
      }
}

// ---------------------------------------------------------------- conv+gate
// vg: [8192][8192] f16 (v = cols 0..4095, g = cols 4096..8191)
// wp: [128][4096] packed f16 weight pairs ; y: [8192][4096] f16
// Block: 64 channels x 128 l-outputs; 4 waves x 32 l's, lane=channel.
// All operands LDS-resident with immediate ds offsets; g gate values
// preloaded into registers BEFORE the FIR loop so their ~400cyc L3 latency
// hides under ~5000cyc of fdot2 issue.
#define CONV_L 128
#define CPAIRS 127  // (CONV_L + 126) / 2

__global__ __launch_bounds__(256) void conv_gate(
    const f16_t* __restrict__ vg, const h2_t* __restrict__ wp,
    const float* __restrict__ b_dw, f16_t* __restrict__ y) {
  __shared__ uint32_t vtp[CPAIRS * 64];  // 32.5 KB
  __shared__ uint32_t wpl[128 * 64];     // 32 KB
  const int t = threadIdx.x;
  const int lane = t & 63;
  const int wave = t >> 6;
  const int c0 = blockIdx.x * 64;
  const int lt = blockIdx.y & 31;   // 4096/128 l-tiles
  const int b = blockIdx.y >> 5;
  const int l0 = lt * CONV_L;

  // stage weight pairs wp[p][c0..c0+63] -> wpl via global->LDS DMA
#pragma unroll
  for (int it = 0; it < 8; ++it) {
    const int q = it * 256 + t;  // 2048 16B chunks: row = q>>4, 4 words each
    async_copy_16B(wp + (size_t)(q >> 4) * 4096 + c0 + (q & 15) * 4,
                   wpl + q * 4);
  }
  // stage v rows [l0-126, l0+127] pair-interleaved (zeros for l<0)
  for (int q = t; q < CPAIRS * 8; q += 256) {
    const int m = q >> 3;
    const int oc = (q & 7) * 8;
    const int le = l0 - 126 + 2 * m;  // always even
    uint4 a = make_uint4(0u, 0u, 0u, 0u);
    uint4 bb = make_uint4(0u, 0u, 0u, 0u);
    if (le >= 0) {
      const size_t base = (size_t)(b * 4096 + le) * 8192 + c0 + oc;
      a = *(const uint4*)(vg + base);
      bb = *(const uint4*)(vg + base + 8192);
    }
    uint32_t* dst = vtp + m * 64 + oc;
    const uint32_t aw[4] = {a.x, a.y, a.z, a.w};
    const uint32_t bw[4] = {bb.x, bb.y, bb.z, bb.w};
#pragma unroll
    for (int i = 0; i < 4; ++i) {
      dst[2 * i] = (aw[i] & 0xFFFFu) | (bw[i] << 16);
      dst[2 * i + 1] = (aw[i] >> 16) | (bw[i] & 0xFFFF0000u);
    }
  }

  const int c = c0 + lane;
  const int lb = l0 + wave * 32;
  // preload gate values (independent of LDS staging; latency hidden by FIR)
  const f16_t* gp = vg + (size_t)(b * 4096 + lb) * 8192 + 4096 + c;
  f16_t gvals[32];
#pragma unroll
  for (int i = 0; i < 32; ++i) gvals[i] = gp[(size_t)i * 8192];

  __syncthreads();

  const float bias = b_dw[c];
  float acc[32];
#pragma unroll
  for (int i = 0; i < 32; ++i) acc[i] = bias;

  // single-base immediate-offset LDS pointers
  const uint32_t* vbase = vtp + wave * 16 * 64 + lane;  // pair index of v[r0]
  const uint32_t* wbase = wpl + lane;

  // ring slot m holds pair (v[r0+2m], v[r0+2m+1]); slots 0..16
  h2_t ring[17];
#pragma unroll
  for (int m = 0; m < 17; ++m)
    ring[m] = __builtin_bit_cast(h2_t, vbase[m * 64]);

  // tap 0 for odd outputs: weight (0, w[0]) = wpl row 127
  {
    const h2_t w0 = __builtin_bit_cast(h2_t, wbase[127 * 64]);
#pragma unroll
    for (int h = 0; h < 16; ++h)
      acc[2 * h + 1] =
          __builtin_amdgcn_fdot2(w0, ring[h], acc[2 * h + 1], false);
  }

  // step k: even outs use row 2k (taps 2k,2k+1); odd outs row 2k+1
#pragma unroll
  for (int k = 0; k < 64; ++k) {
    const h2_t we = __builtin_bit_cast(h2_t, wbase[(2 * k) * 64]);
#pragma unroll
    for (int h = 0; h < 16; ++h)
      acc[2 * h] =
          __builtin_amdgcn_fdot2(we, ring[(k + h) % 17], acc[2 * h], false);
    if (k < 63) {
      const h2_t wo = __builtin_bit_cast(h2_t, wbase[(2 * k + 1) * 64]);
#pragma unroll
      for (int h = 0; h < 16; ++h)
        acc[2 * h + 1] = __builtin_amdgcn_fdot2(wo, ring[(k + 1 + h) % 17],
                                                acc[2 * h + 1], false);
      if (k < 62)  // slide: slot k%17 <- pair k+17
        ring[k % 17] = __builtin_bit_cast(h2_t, vbase[(17 + k) * 64]);
    }
  }

  f16_t* yp = y + (size_t)(b * 4096 + lb) * 4096 + c;
#pragma unroll
  for (int i = 0; i < 32; ++i) {
    const float gv = (float)gvals[i];
    const float v = acc[i];
    const float sv = v / (1.f + __expf(-v));
    const float sg = gv / (1.f + __expf(-gv));
    yp[(size_t)i * 4096] = (f16_t)(sv * sg);
  }
}

// ---------------------------------------------------------------- launch
extern "C" void kernel_launch(void* const* d_in, const int* in_sizes, int n_in,
                              void* d_out, int out_size, void* d_ws,
                              size_t ws_size, hipStream_t stream) {
  const float* x     = (const float*)d_in[0];  // [2,4096,1024]
  const float* w_in  = (const float*)d_in[1];  // [8192,1024]
  const float* w_dw  = (const float*)d_in[2];  // [4096,127]
  const float* b_dw  = (const float*)d_in[3];  // [4096]
  const float* w_out = (const float*)d_in[4];  // [1024,4096]
  float* out = (float*)d_out;                  // [2,4096,1024]

  char* p = (char*)d_ws;
  f16_t* x_h  = (f16_t*)p; p += (size_t)8192 * 1024 * 2;
  f16_t* wi_h = (f16_t*)p; p += (size_t)8192 * 1024 * 2;
  f16_t* wo_h = (f16_t*)p; p += (size_t)1024 * 4096 * 2;
  h2_t*  wp   = (h2_t*)p;  p += (size_t)128 * 4096 * 4;
  f16_t* vg   = (f16_t*)p; p += (size_t)8192 * 8192 * 2;
  f16_t* y    = (f16_t*)p; p += (size_t)8192 * 4096 * 2;

  // fused casts + packed weight-pair build
  prep<<<22528, 256, 0, stream>>>(x, w_in, w_out, w_dw, x_h, wi_h, wo_h, wp);

  // vg[8192,8192] = x[8192,1024] @ w_in[8192,1024]^T  (8-phase 256^2 tile)
  hipFuncSetAttribute(reinterpret_cast<const void*>(gemm256_8p),
                      hipFuncAttributeMaxDynamicSharedMemorySize, 131072);
  gemm256_8p<<<1024, 512, 131072, stream>>>(x_h, wi_h, vg, 8192, 8192, 1024);

  // y = silu(causal_dwconv(v)+b) * silu(g)
  conv_gate<<<dim3(64, 64), 256, 0, stream>>>(vg, wp, b_dw, y);
  // out[8192,1024] = y[8192,4096] @ w_out[1024,4096]^T (BK=128, 3 blk/CU)
  gemm_bt_k128<<<dim3(16, 64), 256, 0, stream>>>(y, wo_h, out,
                                                 8192, 1024, 4096);
}

// Round 2
// 494.983 us; speedup vs baseline: 1.0155x; 1.0155x over previous
//
#include <hip/hip_runtime.h>
#include <hip/hip_bf16.h>
#include <cstdint>
#include <cstddef>

typedef __fp16 f16_t;
typedef __attribute__((ext_vector_type(8))) __fp16 f16x8;
typedef __attribute__((ext_vector_type(4))) __fp16 f16x4;
typedef __attribute__((ext_vector_type(2))) __fp16 h2_t;
typedef __attribute__((ext_vector_type(4))) float floatx4;

// ---------------------------------------------------------------- helpers
__device__ __forceinline__ void async_copy_16B(const void* g, void* l) {
  __builtin_amdgcn_global_load_lds(
      (const __attribute__((address_space(1))) void*)g,
      (__attribute__((address_space(3))) void*)l, 16, 0, 0);
}

// ---------------------------------------------------------------- prep
// Fused: cast x/w_in/w_out to f16 (5242880 float4s) and build packed f16
// weight-pair table wp[p][c], p=0..127:
//   p<126 : (w[p], w[p+1]) ; p==126 : (w[126], 0) ; p==127 : (0, w[0])
__global__ __launch_bounds__(256) void prep(
    const float* __restrict__ x, const float* __restrict__ w_in,
    const float* __restrict__ w_out, const float* __restrict__ w_dw,
    f16_t* __restrict__ x_h, f16_t* __restrict__ wi_h,
    f16_t* __restrict__ wo_h, h2_t* __restrict__ wp) {
  const int tid = blockIdx.x * 256 + threadIdx.x;
  if (tid < 5242880) {
    const float* src;
    f16_t* dst;
    int off;
    if (tid < 2097152) {
      src = x; dst = x_h; off = tid;
    } else if (tid < 4194304) {
      src = w_in; dst = wi_h; off = tid - 2097152;
    } else {
      src = w_out; dst = wo_h; off = tid - 4194304;
    }
    const float4 v = *(const float4*)(src + (size_t)off * 4);
    f16x4 o;
    o.x = (f16_t)v.x; o.y = (f16_t)v.y; o.z = (f16_t)v.z; o.w = (f16_t)v.w;
    *(f16x4*)(dst + (size_t)off * 4) = o;
  } else {
    const int idx = tid - 5242880;
    if (idx < 128 * 4096) {
      const int p = idx >> 12;
      const int c = idx & 4095;
      float a, b;
      if (p < 126) {
        a = w_dw[c * 127 + p]; b = w_dw[c * 127 + p + 1];
      } else if (p == 126) {
        a = w_dw[c * 127 + 126]; b = 0.f;
      } else {
        a = 0.f; b = w_dw[c * 127 + 0];
      }
      h2_t w;
      w.x = (f16_t)a; w.y = (f16_t)b;
      wp[idx] = w;
    }
  }
}

// ---------------------------------------------------------------- GEMM1
// 256x256 tile, BK=64, 8 waves (2M x 4N), 4 phases/K-tile, 2-tile-deep
// rolling prefetch on a 2-buffer LDS ring, ONE counted-vmcnt gate per
// K-tile, XOR-swizzled LDS (linear DMA dest + inverse-swizzled global
// source), setprio around MFMA, quad-rectangular XCD swizzle.
//
// LDS layout per buffer d (d*65536): A[256][64] f16 at +0, B[256][64]
// at +32768. Row = 128 B = 8 x 16B slots; slot s of row r holds k8-group
// s^(r&7) (bank-conflict-free ds_read_b128, verified: conflicts == 0).
//
// Region lifetimes within tile t (reading buffer d, barrier-separated):
//   B(d) dead after p0 ; A-chunk q of d dead after phase q.
// Staging ledger (per-thread loads, in-order; unit sizes: B-half = 2
// loads, A-chunk = 1 load):
//   p0: A3(t+1) -> d^1       (A3(d^1) last read at t-1:p3)
//   p1: Blo(t+2)+A0(t+2) -> d (both dead after t:p0)
//   p2: Bhi(t+2)+A1(t+2) -> d
//   p3: A2(t+2) -> d
//   gate end-p3: 7 units issued after A3(t+1) -> s_waitcnt vmcnt(7)
//   lands ALL of tile t+1 (in-order retirement); barrier makes it
//   collective. Landing windows: 4-7 phases (covers L2-miss latency).
// Tail: tt+2==kT -> no p1-p3 stages, gate vmcnt(0); last tile: none.
__global__ __launch_bounds__(512, 2) void gemm256_8p(
    const f16_t* __restrict__ A, const f16_t* __restrict__ B,
    f16_t* __restrict__ C, int M, int N, int K) {
  extern __shared__ char smem[];
  const int t = threadIdx.x;
  const int lane = t & 63;
  const int wave = t >> 6;
  const int wm = wave >> 2;  // 0..1 : 128-row half
  const int wn = wave & 3;   // 0..3 : 64-col strip

  // XCD swizzle: XCD c owns an 8m x 16n chunk of the 32x32 tile grid,
  // filled quad-by-quad (4m x 8n). First-resident 32 blocks/XCD share a
  // 4x8 rectangle: A 4-way + B 8-way reuse, 6 MB working set (vs 16.5 MB
  // for a full tile-row). Bijective for grid 1024.
  const int bid = blockIdx.x;
  const int xcd = bid & 7;
  const int l = bid >> 3;      // 0..127
  const int quad = l >> 5;     // 0..3
  const int qm = (l >> 3) & 3; // 0..3
  const int qn = l & 7;        // 0..7
  const int m0 = ((xcd >> 1) * 8 + (quad >> 1) * 4 + qm) * 256;
  const int n0 = ((xcd & 1) * 16 + (quad & 1) * 8 + qn) * 256;

  const int fr = lane & 15;
  const int ks = lane >> 4;  // k8-group within K=32 half

  auto stageB = [&](int d, int k0, int half) {
#pragma unroll
    for (int u = 0; u < 2; ++u) {
      const int q = u * 512 + t;
      const int row = half * 128 + (q >> 3);
      const int slot = q & 7;
      const int col = (slot ^ (row & 7)) * 8;  // inverse-swizzled source
      async_copy_16B(B + (size_t)(n0 + row) * K + k0 + col,
                     smem + d * 65536 + 32768 + row * 128 + slot * 16);
    }
  };
  auto stageA = [&](int d, int k0, int j) {
    const int blk = t >> 8;  // 0: rows 32j.., 1: rows 128+32j..
    const int row = j * 32 + blk * 128 + ((t & 255) >> 3);
    const int slot = t & 7;
    const int col = (slot ^ (row & 7)) * 8;
    async_copy_16B(A + (size_t)(m0 + row) * K + k0 + col,
                   smem + d * 65536 + row * 128 + slot * 16);
  };
  auto ldA = [&](int d, int R, int kslot) -> f16x8 {
    return *(const f16x8*)(smem + d * 65536 + R * 128 +
                           ((kslot ^ (R & 7)) << 4));
  };
  auto ldB = [&](int d, int R, int kslot) -> f16x8 {
    return *(const f16x8*)(smem + d * 65536 + 32768 + R * 128 +
                           ((kslot ^ (R & 7)) << 4));
  };

  floatx4 acc[8][4] = {};
  const int kTiles = K / 64;  // >= 2

  // ---- prologue: tile0 (8 loads) + tile1 minus A3 (7 loads) ----
  stageB(0, 0, 0); stageB(0, 0, 1);
  stageA(0, 0, 0); stageA(0, 0, 1); stageA(0, 0, 2); stageA(0, 0, 3);
  stageB(1, 64, 0); stageA(1, 64, 0);
  stageB(1, 64, 1); stageA(1, 64, 1);
  stageA(1, 64, 2);
  asm volatile("s_waitcnt vmcnt(7)" ::: "memory");  // tile0 fully landed
  __builtin_amdgcn_s_barrier();

  f16x8 bf[4][2];
  for (int tt = 0; tt < kTiles; ++tt) {
    const int d = tt & 1;
    const int k1 = (tt + 1) * 64;
    const int k2 = (tt + 2) * 64;
    const bool pf1 = (tt + 1 < kTiles);
    const bool pf2 = (tt + 2 < kTiles);
#pragma unroll
    for (int q = 0; q < 4; ++q) {
      // ds-reads for this phase (A chunk q; B once per tile, reg-resident)
      f16x8 af[2][2];
#pragma unroll
      for (int kh = 0; kh < 2; ++kh) {
#pragma unroll
        for (int ii = 0; ii < 2; ++ii)
          af[ii][kh] = ldA(d, wm * 128 + q * 32 + ii * 16 + fr, kh * 4 + ks);
        if (q == 0)
#pragma unroll
          for (int j = 0; j < 4; ++j)
            bf[j][kh] = ldB(d, wn * 64 + j * 16 + fr, kh * 4 + ks);
      }
      // rolling prefetch issue (regions dead per the lifetime ledger)
      if (q == 0) {
        if (pf1) stageA(d ^ 1, k1, 3);
      } else if (q == 1) {
        if (pf2) { stageB(d, k2, 0); stageA(d, k2, 0); }
      } else if (q == 2) {
        if (pf2) { stageB(d, k2, 1); stageA(d, k2, 1); }
      } else {
        if (pf2) {
          stageA(d, k2, 2);
          asm volatile("s_waitcnt vmcnt(7)" ::: "memory");  // tile t+1 landed
        } else if (pf1) {
          asm volatile("s_waitcnt vmcnt(0)" ::: "memory");
        }
      }
      __builtin_amdgcn_s_barrier();
      asm volatile("s_waitcnt lgkmcnt(0)" ::: "memory");
      __builtin_amdgcn_s_setprio(1);
#pragma unroll
      for (int kh = 0; kh < 2; ++kh)
#pragma unroll
        for (int ii = 0; ii < 2; ++ii)
#pragma unroll
          for (int j = 0; j < 4; ++j)
            acc[q * 2 + ii][j] = __builtin_amdgcn_mfma_f32_16x16x32_f16(
                af[ii][kh], bf[j][kh], acc[q * 2 + ii][j], 0, 0, 0);
      __builtin_amdgcn_s_setprio(0);
      __builtin_amdgcn_s_barrier();  // phase reads fully consumed before
                                     // next phase stages over dead regions
    }
  }

  // C/D layout: col = lane&15, row = (lane>>4)*4 + reg
  const int cr = (lane >> 4) * 4;
  const int cc = lane & 15;
#pragma unroll
  for (int i = 0; i < 8; ++i)
#pragma unroll
    for (int j = 0; j < 4; ++j)
#pragma unroll
      for (int r = 0; r < 4; ++r) {
        const int row = m0 + wm * 128 + i * 16 + cr + r;
        const int col = n0 + wn * 64 + j * 16 + cc;
        C[(size_t)row * N + col] = (f16_t)acc[i][j][r];
      }
}

// ---------------------------------------------------------------- GEMM2
// BK=128 variant for the long-K (K=4096) out-projection: 4x 32-col panels,
// 48 KB LDS (3 blocks/CU), 32 K-tiles -> half the barrier drains of BK=64.
// BM=128, BN=64; wave w computes rows [w*32, w*32+32) x all 64 cols.
__global__ __launch_bounds__(256) void gemm_bt_k128(
    const f16_t* __restrict__ A, const f16_t* __restrict__ B,
    float* __restrict__ C, int M, int N, int K) {
  constexpr int BM_ = 128, BN_ = 64, KP = 4;
  constexpr int NA = BM_ * 4 * KP;            // 2048 A-chunks per K-tile
  constexpr int NTOT = (BM_ + BN_) * 4 * KP;  // 3072 chunks
  constexpr int CPT = NTOT / 256;             // 12

  __shared__ f16_t smem[(BM_ + BN_) * 128];  // 48 KB
  const int t = threadIdx.x;
  const int lane = t & 63;
  const int wave = t >> 6;
  const int m0 = blockIdx.y * BM_;
  const int n0 = blockIdx.x * BN_;
  const int wr = wave * 32;
  const int fr = lane & 15;
  const int fk = (lane >> 4) * 8;

  floatx4 acc[2][4] = {};

  const int kTiles = K / 128;
  for (int kt = 0; kt < kTiles; ++kt) {
    const int k0 = kt * 128;
    __syncthreads();
#pragma unroll
    for (int it = 0; it < CPT; ++it) {
      const int p = it * 256 + t;
      const f16_t* gsrc;
      if (p < NA) {
        const int h = p >> 9;               // panel 0..3
        const int r = (p >> 2) & (BM_ - 1);
        const int kc = h * 32 + (p & 3) * 8;
        gsrc = A + (size_t)(m0 + r) * K + k0 + kc;
      } else {
        const int q = p - NA;
        const int h = q >> 8;
        const int r = (q >> 2) & (BN_ - 1);
        const int kc = h * 32 + (q & 3) * 8;
        gsrc = B + (size_t)(n0 + r) * K + k0 + kc;
      }
      async_copy_16B(gsrc, smem + p * 8);
    }
    __syncthreads();

#pragma unroll
    for (int h = 0; h < KP; ++h) {
      f16x8 af[2], bf[4];
#pragma unroll
      for (int i = 0; i < 2; ++i)
        af[i] = *(const f16x8*)(smem + h * BM_ * 32 + (wr + i * 16 + fr) * 32 + fk);
#pragma unroll
      for (int j = 0; j < 4; ++j)
        bf[j] = *(const f16x8*)(smem + NA * 8 + h * BN_ * 32 + (j * 16 + fr) * 32 + fk);
#pragma unroll
      for (int i = 0; i < 2; ++i)
#pragma unroll
        for (int j = 0; j < 4; ++j)
          acc[i][j] = __builtin_amdgcn_mfma_f32_16x16x32_f16(
              af[i], bf[j], acc[i][j], 0, 0, 0);
    }
  }

  const int cr = (lane >> 4) * 4;
  const int cc = lane & 15;
#pragma unroll
  for (int i = 0; i < 2; ++i)
#pragma unroll
    for (int j = 0; j < 4; ++j)
#pragma unroll
      for (int r = 0; r < 4; ++r) {
        const int row = m0 + wr + i * 16 + cr + r;
        const int col = n0 + j * 16 + cc;
        C[(size_t)row * N + col] = acc[i][j][r];
      }
}

// ---------------------------------------------------------------- conv+gate
// vg: [8192][8192] f16 (v = cols 0..4095, g = cols 4096..8191)
// wp: [128][4096] packed f16 weight pairs ; y: [8192][4096] f16
// Block: 64 channels x 128 l-outputs; 4 waves x 32 l's, lane=channel.
#define CONV_L 128
#define CPAIRS 127  // (CONV_L + 126) / 2

__global__ __launch_bounds__(256) void conv_gate(
    const f16_t* __restrict__ vg, const h2_t* __restrict__ wp,
    const float* __restrict__ b_dw, f16_t* __restrict__ y) {
  __shared__ uint32_t vtp[CPAIRS * 64];  // 32.5 KB
  __shared__ uint32_t wpl[128 * 64];     // 32 KB
  const int t = threadIdx.x;
  const int lane = t & 63;
  const int wave = t >> 6;
  const int c0 = blockIdx.x * 64;
  const int lt = blockIdx.y & 31;   // 4096/128 l-tiles
  const int b = blockIdx.y >> 5;
  const int l0 = lt * CONV_L;

  // stage weight pairs wp[p][c0..c0+63] -> wpl via global->LDS DMA
#pragma unroll
  for (int it = 0; it < 8; ++it) {
    const int q = it * 256 + t;  // 2048 16B chunks: row = q>>4, 4 words each
    async_copy_16B(wp + (size_t)(q >> 4) * 4096 + c0 + (q & 15) * 4,
                   wpl + q * 4);
  }
  // stage v rows [l0-126, l0+127] pair-interleaved (zeros for l<0)
  for (int q = t; q < CPAIRS * 8; q += 256) {
    const int m = q >> 3;
    const int oc = (q & 7) * 8;
    const int le = l0 - 126 + 2 * m;  // always even
    uint4 a = make_uint4(0u, 0u, 0u, 0u);
    uint4 bb = make_uint4(0u, 0u, 0u, 0u);
    if (le >= 0) {
      const size_t base = (size_t)(b * 4096 + le) * 8192 + c0 + oc;
      a = *(const uint4*)(vg + base);
      bb = *(const uint4*)(vg + base + 8192);
    }
    uint32_t* dst = vtp + m * 64 + oc;
    const uint32_t aw[4] = {a.x, a.y, a.z, a.w};
    const uint32_t bw[4] = {bb.x, bb.y, bb.z, bb.w};
#pragma unroll
    for (int i = 0; i < 4; ++i) {
      dst[2 * i] = (aw[i] & 0xFFFFu) | (bw[i] << 16);
      dst[2 * i + 1] = (aw[i] >> 16) | (bw[i] & 0xFFFF0000u);
    }
  }

  const int c = c0 + lane;
  const int lb = l0 + wave * 32;
  // preload gate values (independent of LDS staging; latency hidden by FIR)
  const f16_t* gp = vg + (size_t)(b * 4096 + lb) * 8192 + 4096 + c;
  f16_t gvals[32];
#pragma unroll
  for (int i = 0; i < 32; ++i) gvals[i] = gp[(size_t)i * 8192];

  __syncthreads();

  const float bias = b_dw[c];
  float acc[32];
#pragma unroll
  for (int i = 0; i < 32; ++i) acc[i] = bias;

  // single-base immediate-offset LDS pointers
  const uint32_t* vbase = vtp + wave * 16 * 64 + lane;  // pair index of v[r0]
  const uint32_t* wbase = wpl + lane;

  // ring slot m holds pair (v[r0+2m], v[r0+2m+1]); slots 0..16
  h2_t ring[17];
#pragma unroll
  for (int m = 0; m < 17; ++m)
    ring[m] = __builtin_bit_cast(h2_t, vbase[m * 64]);

  // tap 0 for odd outputs: weight (0, w[0]) = wpl row 127
  {
    const h2_t w0 = __builtin_bit_cast(h2_t, wbase[127 * 64]);
#pragma unroll
    for (int h = 0; h < 16; ++h)
      acc[2 * h + 1] =
          __builtin_amdgcn_fdot2(w0, ring[h], acc[2 * h + 1], false);
  }

  // step k: even outs use row 2k (taps 2k,2k+1); odd outs row 2k+1
#pragma unroll
  for (int k = 0; k < 64; ++k) {
    const h2_t we = __builtin_bit_cast(h2_t, wbase[(2 * k) * 64]);
#pragma unroll
    for (int h = 0; h < 16; ++h)
      acc[2 * h] =
          __builtin_amdgcn_fdot2(we, ring[(k + h) % 17], acc[2 * h], false);
    if (k < 63) {
      const h2_t wo = __builtin_bit_cast(h2_t, wbase[(2 * k + 1) * 64]);
#pragma unroll
      for (int h = 0; h < 16; ++h)
        acc[2 * h + 1] = __builtin_amdgcn_fdot2(wo, ring[(k + 1 + h) % 17],
                                                acc[2 * h + 1], false);
      if (k < 62)  // slide: slot k%17 <- pair k+17
        ring[k % 17] = __builtin_bit_cast(h2_t, vbase[(17 + k) * 64]);
    }
  }

  f16_t* yp = y + (size_t)(b * 4096 + lb) * 4096 + c;
#pragma unroll
  for (int i = 0; i < 32; ++i) {
    const float gv = (float)gvals[i];
    const float v = acc[i];
    const float sv = v / (1.f + __expf(-v));
    const float sg = gv / (1.f + __expf(-gv));
    yp[(size_t)i * 4096] = (f16_t)(sv * sg);
  }
}

// ---------------------------------------------------------------- launch
extern "C" void kernel_launch(void* const* d_in, const int* in_sizes, int n_in,
                              void* d_out, int out_size, void* d_ws,
                              size_t ws_size, hipStream_t stream) {
  const float* x     = (const float*)d_in[0];  // [2,4096,1024]
  const float* w_in  = (const float*)d_in[1];  // [8192,1024]
  const float* w_dw  = (const float*)d_in[2];  // [4096,127]
  const float* b_dw  = (const float*)d_in[3];  // [4096]
  const float* w_out = (const float*)d_in[4];  // [1024,4096]
  float* out = (float*)d_out;                  // [2,4096,1024]

  char* p = (char*)d_ws;
  f16_t* x_h  = (f16_t*)p; p += (size_t)8192 * 1024 * 2;
  f16_t* wi_h = (f16_t*)p; p += (size_t)8192 * 1024 * 2;
  f16_t* wo_h = (f16_t*)p; p += (size_t)1024 * 4096 * 2;
  h2_t*  wp   = (h2_t*)p;  p += (size_t)128 * 4096 * 4;
  f16_t* vg   = (f16_t*)p; p += (size_t)8192 * 8192 * 2;
  f16_t* y    = (f16_t*)p; p += (size_t)8192 * 4096 * 2;

  // fused casts + packed weight-pair build
  prep<<<22528, 256, 0, stream>>>(x, w_in, w_out, w_dw, x_h, wi_h, wo_h, wp);

  // vg[8192,8192] = x[8192,1024] @ w_in[8192,1024]^T  (deep-pipelined 256^2)
  hipFuncSetAttribute(reinterpret_cast<const void*>(gemm256_8p),
                      hipFuncAttributeMaxDynamicSharedMemorySize, 131072);
  gemm256_8p<<<1024, 512, 131072, stream>>>(x_h, wi_h, vg, 8192, 8192, 1024);

  // y = silu(causal_dwconv(v)+b) * silu(g)
  conv_gate<<<dim3(64, 64), 256, 0, stream>>>(vg, wp, b_dw, y);
  // out[8192,1024] = y[8192,4096] @ w_out[1024,4096]^T (BK=128, 3 blk/CU)
  gemm_bt_k128<<<dim3(16, 64), 256, 0, stream>>>(y, wo_h, out,
                                                 8192, 1024, 4096);
}

// Round 3
// 444.379 us; speedup vs baseline: 1.1311x; 1.1139x over previous
//
#include <hip/hip_runtime.h>
#include <hip/hip_bf16.h>
#include <cstdint>
#include <cstddef>

typedef __fp16 f16_t;
typedef __attribute__((ext_vector_type(8))) __fp16 f16x8;
typedef __attribute__((ext_vector_type(4))) __fp16 f16x4;
typedef __attribute__((ext_vector_type(2))) __fp16 h2_t;
typedef __attribute__((ext_vector_type(4))) float floatx4;

// ---------------------------------------------------------------- helpers
__device__ __forceinline__ void async_copy_16B(const void* g, void* l) {
  __builtin_amdgcn_global_load_lds(
      (const __attribute__((address_space(1))) void*)g,
      (__attribute__((address_space(3))) void*)l, 16, 0, 0);
}

// ---------------------------------------------------------------- prep
// Fused: cast x/w_in/w_out to f16 (5242880 float4s) and build packed f16
// weight-pair table wp[p][c], p=0..127:
//   p<126 : (w[p], w[p+1]) ; p==126 : (w[126], 0) ; p==127 : (0, w[0])
__global__ __launch_bounds__(256) void prep(
    const float* __restrict__ x, const float* __restrict__ w_in,
    const float* __restrict__ w_out, const float* __restrict__ w_dw,
    f16_t* __restrict__ x_h, f16_t* __restrict__ wi_h,
    f16_t* __restrict__ wo_h, h2_t* __restrict__ wp) {
  const int tid = blockIdx.x * 256 + threadIdx.x;
  if (tid < 5242880) {
    const float* src;
    f16_t* dst;
    int off;
    if (tid < 2097152) {
      src = x; dst = x_h; off = tid;
    } else if (tid < 4194304) {
      src = w_in; dst = wi_h; off = tid - 2097152;
    } else {
      src = w_out; dst = wo_h; off = tid - 4194304;
    }
    const float4 v = *(const float4*)(src + (size_t)off * 4);
    f16x4 o;
    o.x = (f16_t)v.x; o.y = (f16_t)v.y; o.z = (f16_t)v.z; o.w = (f16_t)v.w;
    *(f16x4*)(dst + (size_t)off * 4) = o;
  } else {
    const int idx = tid - 5242880;
    if (idx < 128 * 4096) {
      const int p = idx >> 12;
      const int c = idx & 4095;
      float a, b;
      if (p < 126) {
        a = w_dw[c * 127 + p]; b = w_dw[c * 127 + p + 1];
      } else if (p == 126) {
        a = w_dw[c * 127 + 126]; b = 0.f;
      } else {
        a = 0.f; b = w_dw[c * 127 + 0];
      }
      h2_t w;
      w.x = (f16_t)a; w.y = (f16_t)b;
      wp[idx] = w;
    }
  }
}

// ---------------------------------------------------------------- GEMM1
// 256x256 tile, BK=64, 8 waves (2M x 4N), ONE phase per K-tile:
//   stage(t+1 -> d^1)  ->  s_waitcnt vmcnt(8)  ->  barrier
//   -> ds_read frags + 64 MFMA/wave (compiler-interleaved lgkmcnt)
//   -> barrier
// Counted gate: tile t's 8 loads/thread were issued one full phase ago;
// after issuing tile t+1's 8, vmcnt(8) retires exactly tile t. Never 0
// in steady state. 128 KiB LDS double buffer, XOR-swizzled rows (linear
// DMA dest + inverse-swizzled global source). Quad-rect XCD swizzle
// (verified: FETCH 270->98 MB). Barrier pairs per K-tile: 2 (was 8).
__global__ __launch_bounds__(512, 2) void gemm256_1p(
    const f16_t* __restrict__ A, const f16_t* __restrict__ B,
    f16_t* __restrict__ C, int M, int N, int K) {
  extern __shared__ char smem[];
  const int t = threadIdx.x;
  const int lane = t & 63;
  const int wave = t >> 6;
  const int wm = wave >> 2;  // 0..1 : 128-row half
  const int wn = wave & 3;   // 0..3 : 64-col strip

  // XCD swizzle: XCD c owns an 8m x 16n chunk of the 32x32 tile grid,
  // filled quad-by-quad (4m x 8n). Bijective for grid 1024.
  const int bid = blockIdx.x;
  const int xcd = bid & 7;
  const int l = bid >> 3;      // 0..127
  const int quad = l >> 5;     // 0..3
  const int qm = (l >> 3) & 3; // 0..3
  const int qn = l & 7;        // 0..7
  const int m0 = ((xcd >> 1) * 8 + (quad >> 1) * 4 + qm) * 256;
  const int n0 = ((xcd & 1) * 16 + (quad & 1) * 8 + qn) * 256;

  const int fr = lane & 15;
  const int ks = lane >> 4;  // k8-group within K=32 half

  auto stageTile = [&](int d, int k0) {
#pragma unroll
    for (int u = 0; u < 4; ++u) {
      const int q = u * 512 + t;
      const int row = q >> 3, slot = q & 7;
      const int col = (slot ^ (row & 7)) * 8;  // inverse-swizzled source
      async_copy_16B(A + (size_t)(m0 + row) * K + k0 + col,
                     smem + d * 65536 + row * 128 + slot * 16);
    }
#pragma unroll
    for (int u = 0; u < 4; ++u) {
      const int q = u * 512 + t;
      const int row = q >> 3, slot = q & 7;
      const int col = (slot ^ (row & 7)) * 8;
      async_copy_16B(B + (size_t)(n0 + row) * K + k0 + col,
                     smem + d * 65536 + 32768 + row * 128 + slot * 16);
    }
  };
  auto ldA = [&](int d, int R, int kslot) -> f16x8 {
    return *(const f16x8*)(smem + d * 65536 + R * 128 +
                           ((kslot ^ (R & 7)) << 4));
  };
  auto ldB = [&](int d, int R, int kslot) -> f16x8 {
    return *(const f16x8*)(smem + d * 65536 + 32768 + R * 128 +
                           ((kslot ^ (R & 7)) << 4));
  };

  floatx4 acc[8][4] = {};
  const int kTiles = K / 64;  // 16

  stageTile(0, 0);
  for (int tt = 0; tt < kTiles; ++tt) {
    const int d = tt & 1;
    const bool pf = (tt + 1 < kTiles);
    if (pf) {
      stageTile(d ^ 1, (tt + 1) * 64);  // d^1 dead since t-1's barrier
      asm volatile("s_waitcnt vmcnt(8)" ::: "memory");  // tile t landed
    } else {
      asm volatile("s_waitcnt vmcnt(0)" ::: "memory");
    }
    __builtin_amdgcn_s_barrier();

    f16x8 bf[4][2];
#pragma unroll
    for (int j = 0; j < 4; ++j)
#pragma unroll
      for (int kh = 0; kh < 2; ++kh)
        bf[j][kh] = ldB(d, wn * 64 + j * 16 + fr, kh * 4 + ks);
    __builtin_amdgcn_s_setprio(1);
#pragma unroll
    for (int ii = 0; ii < 8; ++ii) {
      const f16x8 af0 = ldA(d, wm * 128 + ii * 16 + fr, ks);
      const f16x8 af1 = ldA(d, wm * 128 + ii * 16 + fr, 4 + ks);
#pragma unroll
      for (int j = 0; j < 4; ++j)
        acc[ii][j] = __builtin_amdgcn_mfma_f32_16x16x32_f16(
            af0, bf[j][0], acc[ii][j], 0, 0, 0);
#pragma unroll
      for (int j = 0; j < 4; ++j)
        acc[ii][j] = __builtin_amdgcn_mfma_f32_16x16x32_f16(
            af1, bf[j][1], acc[ii][j], 0, 0, 0);
    }
    __builtin_amdgcn_s_setprio(0);
    __builtin_amdgcn_s_barrier();  // all reads of d done before t+1 stages d
  }

  // C/D layout: col = lane&15, row = (lane>>4)*4 + reg
  const int cr = (lane >> 4) * 4;
  const int cc = lane & 15;
#pragma unroll
  for (int i = 0; i < 8; ++i)
#pragma unroll
    for (int j = 0; j < 4; ++j)
#pragma unroll
      for (int r = 0; r < 4; ++r) {
        const int row = m0 + wm * 128 + i * 16 + cr + r;
        const int col = n0 + wn * 64 + j * 16 + cc;
        C[(size_t)row * N + col] = (f16_t)acc[i][j][r];
      }
}

// ---------------------------------------------------------------- GEMM2
// Deep-pipelined out-projection: BM=256, BN=128, BK=64, 512 thr, 96 KiB
// LDS double buffer, same 1-phase/tile schedule as GEMM1 (counted
// vmcnt(6), never 0 in steady state). Grid = exactly 256 blocks
// (32m x 8n), XCD-mapped: XCD c owns m-rows [4c,4c+4) x all 8 n.
// Per-wave output 128x32 (acc[8][2]), 32 MFMA/wave/tile, 64 K-tiles.
__global__ __launch_bounds__(512, 2) void gemmN128_1p(
    const f16_t* __restrict__ A, const f16_t* __restrict__ B,
    float* __restrict__ C, int M, int N, int K) {
  extern __shared__ char smem[];
  const int t = threadIdx.x;
  const int lane = t & 63;
  const int wave = t >> 6;
  const int wm = wave >> 2;  // 0..1
  const int wn = wave & 3;   // 0..3

  const int bid = blockIdx.x;
  const int xcd = bid & 7;
  const int l = bid >> 3;               // 0..31
  const int m0 = (xcd * 4 + (l >> 3)) * 256;  // 32 m-tiles
  const int n0 = (l & 7) * 128;               // 8 n-tiles

  const int fr = lane & 15;
  const int ks = lane >> 4;

  auto stageTile = [&](int d, int k0) {
#pragma unroll
    for (int u = 0; u < 4; ++u) {  // A: 256x64 = 2048 chunks
      const int q = u * 512 + t;
      const int row = q >> 3, slot = q & 7;
      const int col = (slot ^ (row & 7)) * 8;
      async_copy_16B(A + (size_t)(m0 + row) * K + k0 + col,
                     smem + d * 49152 + row * 128 + slot * 16);
    }
#pragma unroll
    for (int u = 0; u < 2; ++u) {  // B: 128x64 = 1024 chunks
      const int q = u * 512 + t;
      const int row = q >> 3, slot = q & 7;
      const int col = (slot ^ (row & 7)) * 8;
      async_copy_16B(B + (size_t)(n0 + row) * K + k0 + col,
                     smem + d * 49152 + 32768 + row * 128 + slot * 16);
    }
  };
  auto ldA = [&](int d, int R, int kslot) -> f16x8 {
    return *(const f16x8*)(smem + d * 49152 + R * 128 +
                           ((kslot ^ (R & 7)) << 4));
  };
  auto ldB = [&](int d, int R, int kslot) -> f16x8 {
    return *(const f16x8*)(smem + d * 49152 + 32768 + R * 128 +
                           ((kslot ^ (R & 7)) << 4));
  };

  floatx4 acc[8][2] = {};
  const int kTiles = K / 64;  // 64

  stageTile(0, 0);
  for (int tt = 0; tt < kTiles; ++tt) {
    const int d = tt & 1;
    const bool pf = (tt + 1 < kTiles);
    if (pf) {
      stageTile(d ^ 1, (tt + 1) * 64);
      asm volatile("s_waitcnt vmcnt(6)" ::: "memory");  // tile t landed
    } else {
      asm volatile("s_waitcnt vmcnt(0)" ::: "memory");
    }
    __builtin_amdgcn_s_barrier();

    f16x8 bf[2][2];
#pragma unroll
    for (int j = 0; j < 2; ++j)
#pragma unroll
      for (int kh = 0; kh < 2; ++kh)
        bf[j][kh] = ldB(d, wn * 32 + j * 16 + fr, kh * 4 + ks);
    __builtin_amdgcn_s_setprio(1);
#pragma unroll
    for (int ii = 0; ii < 8; ++ii) {
      const f16x8 af0 = ldA(d, wm * 128 + ii * 16 + fr, ks);
      const f16x8 af1 = ldA(d, wm * 128 + ii * 16 + fr, 4 + ks);
#pragma unroll
      for (int j = 0; j < 2; ++j)
        acc[ii][j] = __builtin_amdgcn_mfma_f32_16x16x32_f16(
            af0, bf[j][0], acc[ii][j], 0, 0, 0);
#pragma unroll
      for (int j = 0; j < 2; ++j)
        acc[ii][j] = __builtin_amdgcn_mfma_f32_16x16x32_f16(
            af1, bf[j][1], acc[ii][j], 0, 0, 0);
    }
    __builtin_amdgcn_s_setprio(0);
    __builtin_amdgcn_s_barrier();
  }

  const int cr = (lane >> 4) * 4;
  const int cc = lane & 15;
#pragma unroll
  for (int i = 0; i < 8; ++i)
#pragma unroll
    for (int j = 0; j < 2; ++j)
#pragma unroll
      for (int r = 0; r < 4; ++r) {
        const int row = m0 + wm * 128 + i * 16 + cr + r;
        const int col = n0 + wn * 32 + j * 16 + cc;
        C[(size_t)row * N + col] = acc[i][j][r];
      }
}

// ---------------------------------------------------------------- conv+gate
// vg: [8192][8192] f16 (v = cols 0..4095, g = cols 4096..8191)
// wp: [128][4096] packed f16 weight pairs ; y: [8192][4096] f16
// Block: 64 channels x 128 l-outputs; 4 waves x 32 l's, lane=channel.
#define CONV_L 128
#define CPAIRS 127  // (CONV_L + 126) / 2

__global__ __launch_bounds__(256) void conv_gate(
    const f16_t* __restrict__ vg, const h2_t* __restrict__ wp,
    const float* __restrict__ b_dw, f16_t* __restrict__ y) {
  __shared__ uint32_t vtp[CPAIRS * 64];  // 32.5 KB
  __shared__ uint32_t wpl[128 * 64];     // 32 KB
  const int t = threadIdx.x;
  const int lane = t & 63;
  const int wave = t >> 6;
  const int c0 = blockIdx.x * 64;
  const int lt = blockIdx.y & 31;   // 4096/128 l-tiles
  const int b = blockIdx.y >> 5;
  const int l0 = lt * CONV_L;

  // stage weight pairs wp[p][c0..c0+63] -> wpl via global->LDS DMA
#pragma unroll
  for (int it = 0; it < 8; ++it) {
    const int q = it * 256 + t;  // 2048 16B chunks: row = q>>4, 4 words each
    async_copy_16B(wp + (size_t)(q >> 4) * 4096 + c0 + (q & 15) * 4,
                   wpl + q * 4);
  }
  // stage v rows [l0-126, l0+127] pair-interleaved (zeros for l<0)
  for (int q = t; q < CPAIRS * 8; q += 256) {
    const int m = q >> 3;
    const int oc = (q & 7) * 8;
    const int le = l0 - 126 + 2 * m;  // always even
    uint4 a = make_uint4(0u, 0u, 0u, 0u);
    uint4 bb = make_uint4(0u, 0u, 0u, 0u);
    if (le >= 0) {
      const size_t base = (size_t)(b * 4096 + le) * 8192 + c0 + oc;
      a = *(const uint4*)(vg + base);
      bb = *(const uint4*)(vg + base + 8192);
    }
    uint32_t* dst = vtp + m * 64 + oc;
    const uint32_t aw[4] = {a.x, a.y, a.z, a.w};
    const uint32_t bw[4] = {bb.x, bb.y, bb.z, bb.w};
#pragma unroll
    for (int i = 0; i < 4; ++i) {
      dst[2 * i] = (aw[i] & 0xFFFFu) | (bw[i] << 16);
      dst[2 * i + 1] = (aw[i] >> 16) | (bw[i] & 0xFFFF0000u);
    }
  }

  const int c = c0 + lane;
  const int lb = l0 + wave * 32;
  // preload gate values (independent of LDS staging; latency hidden by FIR)
  const f16_t* gp = vg + (size_t)(b * 4096 + lb) * 8192 + 4096 + c;
  f16_t gvals[32];
#pragma unroll
  for (int i = 0; i < 32; ++i) gvals[i] = gp[(size_t)i * 8192];

  __syncthreads();

  const float bias = b_dw[c];
  float acc[32];
#pragma unroll
  for (int i = 0; i < 32; ++i) acc[i] = bias;

  // single-base immediate-offset LDS pointers
  const uint32_t* vbase = vtp + wave * 16 * 64 + lane;  // pair index of v[r0]
  const uint32_t* wbase = wpl + lane;

  // ring slot m holds pair (v[r0+2m], v[r0+2m+1]); slots 0..16
  h2_t ring[17];
#pragma unroll
  for (int m = 0; m < 17; ++m)
    ring[m] = __builtin_bit_cast(h2_t, vbase[m * 64]);

  // tap 0 for odd outputs: weight (0, w[0]) = wpl row 127
  {
    const h2_t w0 = __builtin_bit_cast(h2_t, wbase[127 * 64]);
#pragma unroll
    for (int h = 0; h < 16; ++h)
      acc[2 * h + 1] =
          __builtin_amdgcn_fdot2(w0, ring[h], acc[2 * h + 1], false);
  }

  // step k: even outs use row 2k (taps 2k,2k+1); odd outs row 2k+1
#pragma unroll
  for (int k = 0; k < 64; ++k) {
    const h2_t we = __builtin_bit_cast(h2_t, wbase[(2 * k) * 64]);
#pragma unroll
    for (int h = 0; h < 16; ++h)
      acc[2 * h] =
          __builtin_amdgcn_fdot2(we, ring[(k + h) % 17], acc[2 * h], false);
    if (k < 63) {
      const h2_t wo = __builtin_bit_cast(h2_t, wbase[(2 * k + 1) * 64]);
#pragma unroll
      for (int h = 0; h < 16; ++h)
        acc[2 * h + 1] = __builtin_amdgcn_fdot2(wo, ring[(k + 1 + h) % 17],
                                                acc[2 * h + 1], false);
      if (k < 62)  // slide: slot k%17 <- pair k+17
        ring[k % 17] = __builtin_bit_cast(h2_t, vbase[(17 + k) * 64]);
    }
  }

  f16_t* yp = y + (size_t)(b * 4096 + lb) * 4096 + c;
#pragma unroll
  for (int i = 0; i < 32; ++i) {
    const float gv = (float)gvals[i];
    const float v = acc[i];
    const float sv = v / (1.f + __expf(-v));
    const float sg = gv / (1.f + __expf(-gv));
    yp[(size_t)i * 4096] = (f16_t)(sv * sg);
  }
}

// ---------------------------------------------------------------- launch
extern "C" void kernel_launch(void* const* d_in, const int* in_sizes, int n_in,
                              void* d_out, int out_size, void* d_ws,
                              size_t ws_size, hipStream_t stream) {
  const float* x     = (const float*)d_in[0];  // [2,4096,1024]
  const float* w_in  = (const float*)d_in[1];  // [8192,1024]
  const float* w_dw  = (const float*)d_in[2];  // [4096,127]
  const float* b_dw  = (const float*)d_in[3];  // [4096]
  const float* w_out = (const float*)d_in[4];  // [1024,4096]
  float* out = (float*)d_out;                  // [2,4096,1024]

  char* p = (char*)d_ws;
  f16_t* x_h  = (f16_t*)p; p += (size_t)8192 * 1024 * 2;
  f16_t* wi_h = (f16_t*)p; p += (size_t)8192 * 1024 * 2;
  f16_t* wo_h = (f16_t*)p; p += (size_t)1024 * 4096 * 2;
  h2_t*  wp   = (h2_t*)p;  p += (size_t)128 * 4096 * 4;
  f16_t* vg   = (f16_t*)p; p += (size_t)8192 * 8192 * 2;
  f16_t* y    = (f16_t*)p; p += (size_t)8192 * 4096 * 2;

  // fused casts + packed weight-pair build
  prep<<<22528, 256, 0, stream>>>(x, w_in, w_out, w_dw, x_h, wi_h, wo_h, wp);

  // vg[8192,8192] = x[8192,1024] @ w_in[8192,1024]^T  (1-phase/tile 256^2)
  hipFuncSetAttribute(reinterpret_cast<const void*>(gemm256_1p),
                      hipFuncAttributeMaxDynamicSharedMemorySize, 131072);
  gemm256_1p<<<1024, 512, 131072, stream>>>(x_h, wi_h, vg, 8192, 8192, 1024);

  // y = silu(causal_dwconv(v)+b) * silu(g)
  conv_gate<<<dim3(64, 64), 256, 0, stream>>>(vg, wp, b_dw, y);

  // out[8192,1024] = y[8192,4096] @ w_out[1024,4096]^T (deep 256x128 tile)
  hipFuncSetAttribute(reinterpret_cast<const void*>(gemmN128_1p),
                      hipFuncAttributeMaxDynamicSharedMemorySize, 98304);
  gemmN128_1p<<<256, 512, 98304, stream>>>(y, wo_h, out, 8192, 1024, 4096);
}